// Round 2
// baseline (1083.311 us; speedup 1.0000x reference)
//
#include <hip/hip_runtime.h>
#include <hip/hip_bf16.h>

#define N_NODES 250000
#define N_EDGES 4000000
#define N_GRAPHS 512
#define NEG 0.01f

__device__ __forceinline__ float lrelu(float v) { return v > 0.0f ? v : NEG * v; }

// Layer-1 scatter: 16 lanes per edge (13 active for features, lane 13 counts degree).
__global__ void scatter_l1(const float* __restrict__ x,
                           const int* __restrict__ src,
                           const int* __restrict__ dst,
                           float* __restrict__ agg,
                           float* __restrict__ cnt) {
    unsigned tid = blockIdx.x * blockDim.x + threadIdx.x;
    unsigned e = tid >> 4;
    unsigned j = tid & 15u;
    if (e >= N_EDGES) return;
    int d = dst[e];
    if (j < 13u) {
        int s = src[e];
        atomicAdd(&agg[(unsigned)d * 13u + j], x[(unsigned)s * 13u + j]);
    } else if (j == 13u) {
        atomicAdd(&cnt[d], 1.0f);
    }
}

// Power-of-2-width fp32 scatter for pre-transformed features (layers 2 and 3).
template <int LOGD>
__global__ void scatter_pow2(const float* __restrict__ feat,
                             const int* __restrict__ src,
                             const int* __restrict__ dst,
                             float* __restrict__ agg) {
    unsigned tid = blockIdx.x * blockDim.x + threadIdx.x;
    unsigned e = tid >> LOGD;
    unsigned j = tid & ((1u << LOGD) - 1u);
    if (e >= N_EDGES) return;
    atomicAdd(&agg[((unsigned)dst[e] << LOGD) + j],
              feat[((unsigned)src[e] << LOGD) + j]);
}

// h1 = lrelu(mean_agg(x)@W1l + b1 + x@W1r)  [13->16], fused y2 = h1@W2l [16->8]
__global__ void fused1(const float* __restrict__ agg,
                       const float* __restrict__ x,
                       const float* __restrict__ cnt,
                       const float* __restrict__ W1l,
                       const float* __restrict__ b1,
                       const float* __restrict__ W1r,
                       const float* __restrict__ W2l,
                       float* __restrict__ h1,
                       float* __restrict__ y2) {
    __shared__ float sWl[208], sWr[208], sb[16], sW2[128];
    for (int i = threadIdx.x; i < 208; i += blockDim.x) { sWl[i] = W1l[i]; sWr[i] = W1r[i]; }
    for (int i = threadIdx.x; i < 128; i += blockDim.x) sW2[i] = W2l[i];
    if (threadIdx.x < 16) sb[threadIdx.x] = b1[threadIdx.x];
    __syncthreads();
    int n = blockIdx.x * blockDim.x + threadIdx.x;
    if (n >= N_NODES) return;
    float inv = 1.0f / fmaxf(cnt[n], 1.0f);
    float a[13], xv[13];
#pragma unroll
    for (int i = 0; i < 13; i++) { a[i] = agg[n * 13 + i] * inv; xv[i] = x[n * 13 + i]; }
    float h[16];
#pragma unroll
    for (int o = 0; o < 16; o++) {
        float acc = sb[o];
#pragma unroll
        for (int i = 0; i < 13; i++) acc += a[i] * sWl[i * 16 + o] + xv[i] * sWr[i * 16 + o];
        h[o] = lrelu(acc);
        h1[n * 16 + o] = h[o];
    }
#pragma unroll
    for (int o2 = 0; o2 < 8; o2++) {
        float acc = 0.0f;
#pragma unroll
        for (int o = 0; o < 16; o++) acc += h[o] * sW2[o * 8 + o2];
        y2[n * 8 + o2] = acc;
    }
}

// h2 = lrelu(agg2/cnt + b2 + h1@W2r) [->8], fused y3 = h2@W3l [8->4]
__global__ void fused2(const float* __restrict__ agg2,
                       const float* __restrict__ h1,
                       const float* __restrict__ cnt,
                       const float* __restrict__ W2r,
                       const float* __restrict__ b2,
                       const float* __restrict__ W3l,
                       float* __restrict__ h2,
                       float* __restrict__ y3) {
    __shared__ float sWr[128], sb[8], sW3[32];
    for (int i = threadIdx.x; i < 128; i += blockDim.x) sWr[i] = W2r[i];
    if (threadIdx.x < 8) sb[threadIdx.x] = b2[threadIdx.x];
    if (threadIdx.x < 32) sW3[threadIdx.x] = W3l[threadIdx.x];
    __syncthreads();
    int n = blockIdx.x * blockDim.x + threadIdx.x;
    if (n >= N_NODES) return;
    float inv = 1.0f / fmaxf(cnt[n], 1.0f);
    float hv[16];
#pragma unroll
    for (int i = 0; i < 16; i++) hv[i] = h1[n * 16 + i];
    float h2v[8];
#pragma unroll
    for (int j = 0; j < 8; j++) {
        float acc = agg2[n * 8 + j] * inv + sb[j];
#pragma unroll
        for (int i = 0; i < 16; i++) acc += hv[i] * sWr[i * 8 + j];
        h2v[j] = lrelu(acc);
        h2[n * 8 + j] = h2v[j];
    }
#pragma unroll
    for (int k = 0; k < 4; k++) {
        float acc = 0.0f;
#pragma unroll
        for (int j = 0; j < 8; j++) acc += h2v[j] * sW3[j * 4 + k];
        y3[n * 4 + k] = acc;
    }
}

// h3 = agg3/cnt + b3 + h2@W3r (no relu); pooled into per-graph sums.
// batch is sorted -> block-local LDS window (16 graphs) + fallback.
__global__ void pool_k(const float* __restrict__ agg3,
                       const float* __restrict__ h2,
                       const float* __restrict__ cnt,
                       const float* __restrict__ W3r,
                       const float* __restrict__ b3,
                       const int* __restrict__ batch,
                       float* __restrict__ pool,
                       float* __restrict__ gcnt) {
    __shared__ float sW[32], sb[4];
    __shared__ float lp[16][4];
    __shared__ float lc[16];
    __shared__ int sbase;
    if (threadIdx.x < 32) sW[threadIdx.x] = W3r[threadIdx.x];
    if (threadIdx.x < 4) sb[threadIdx.x] = b3[threadIdx.x];
    if (threadIdx.x < 16) {
        lc[threadIdx.x] = 0.0f;
        for (int k = 0; k < 4; k++) lp[threadIdx.x][k] = 0.0f;
    }
    int n0 = blockIdx.x * blockDim.x;
    if (threadIdx.x == 0) sbase = batch[n0 < N_NODES ? n0 : N_NODES - 1];
    __syncthreads();
    int n = n0 + threadIdx.x;
    if (n < N_NODES) {
        int b = batch[n];
        float inv = 1.0f / fmaxf(cnt[n], 1.0f);
        float h2v[8];
#pragma unroll
        for (int j = 0; j < 8; j++) h2v[j] = h2[n * 8 + j];
        int off = b - sbase;
        bool local = (off >= 0 && off < 16);
#pragma unroll
        for (int k = 0; k < 4; k++) {
            float z = 0.0f;
#pragma unroll
            for (int j = 0; j < 8; j++) z += h2v[j] * sW[j * 4 + k];
            float v = agg3[n * 4 + k] * inv + sb[k] + z;
            if (local) atomicAdd(&lp[off][k], v);
            else atomicAdd(&pool[b * 4 + k], v);
        }
        if (local) atomicAdd(&lc[off], 1.0f);
        else atomicAdd(&gcnt[b], 1.0f);
    }
    __syncthreads();
    if (threadIdx.x < 16) {
        int b = sbase + threadIdx.x;
        float c = lc[threadIdx.x];
        if (c > 0.0f && b < N_GRAPHS) {
            atomicAdd(&gcnt[b], c);
            for (int k = 0; k < 4; k++) atomicAdd(&pool[b * 4 + k], lp[threadIdx.x][k]);
        }
    }
}

// out[g] = sum_k mean_pool*Wc[k] + add_pool*Wc[4+k] + bc
__global__ void final_k(const float* __restrict__ pool,
                        const float* __restrict__ gcnt,
                        const float* __restrict__ Wc,
                        const float* __restrict__ bc,
                        float* __restrict__ out) {
    int g = blockIdx.x * blockDim.x + threadIdx.x;
    if (g >= N_GRAPHS) return;
    float inv = 1.0f / fmaxf(gcnt[g], 1.0f);
    float acc = bc[0];
#pragma unroll
    for (int k = 0; k < 4; k++) {
        float ap = pool[g * 4 + k];
        acc += ap * inv * Wc[k] + ap * Wc[4 + k];
    }
    out[g] = acc;
}

extern "C" void kernel_launch(void* const* d_in, const int* in_sizes, int n_in,
                              void* d_out, int out_size, void* d_ws, size_t ws_size,
                              hipStream_t stream) {
    const float* x = (const float*)d_in[0];
    const int* ei = (const int*)d_in[1];
    const int* src = ei;
    const int* dst = ei + N_EDGES;
    const int* batch = (const int*)d_in[2];
    const float* W1l = (const float*)d_in[3];
    const float* b1 = (const float*)d_in[4];
    const float* W1r = (const float*)d_in[5];
    const float* W2l = (const float*)d_in[6];
    const float* b2 = (const float*)d_in[7];
    const float* W2r = (const float*)d_in[8];
    const float* W3l = (const float*)d_in[9];
    const float* b3 = (const float*)d_in[10];
    const float* W3r = (const float*)d_in[11];
    const float* Wc = (const float*)d_in[12];
    const float* bc = (const float*)d_in[13];
    float* out = (float*)d_out;

    float* ws = (float*)d_ws;
    const size_t N = N_NODES;
    float* cnt = ws;              // N
    float* agg = ws + N;          // 13N (reused as 8N, 4N)
    float* h1 = ws + 14 * N;      // 16N
    float* y2 = ws + 30 * N;      // 8N (reused as h2)
    float* h2 = y2;
    float* y3 = ws + 38 * N;      // 4N
    float* pool = ws + 42 * N;    // 2048
    float* gcnt = pool + N_GRAPHS * 4;  // 512

    const int TPB = 256;

    hipMemsetAsync(cnt, 0, N * 14 * sizeof(float), stream);            // cnt + agg(13)
    hipMemsetAsync(pool, 0, N_GRAPHS * 5 * sizeof(float), stream);     // pool + gcnt

    // Layer 1: scatter raw x (13 dims) + degree, then fused node linear.
    {
        unsigned total = (unsigned)N_EDGES * 16u;
        scatter_l1<<<total / TPB, TPB, 0, stream>>>(x, src, dst, agg, cnt);
        fused1<<<(N_NODES + TPB - 1) / TPB, TPB, 0, stream>>>(agg, x, cnt, W1l, b1, W1r, W2l, h1, y2);
    }

    // Layer 2: scatter pre-transformed y2 (8 dims), fused epilogue + y3.
    {
        hipMemsetAsync(agg, 0, N * 8 * sizeof(float), stream);
        unsigned total = (unsigned)N_EDGES * 8u;
        scatter_pow2<3><<<total / TPB, TPB, 0, stream>>>(y2, src, dst, agg);
        fused2<<<(N_NODES + TPB - 1) / TPB, TPB, 0, stream>>>(agg, h1, cnt, W2r, b2, W3l, h2, y3);
    }

    // Layer 3: scatter y3 (4 dims), fused epilogue + pooling.
    {
        hipMemsetAsync(agg, 0, N * 4 * sizeof(float), stream);
        unsigned total = (unsigned)N_EDGES * 4u;
        scatter_pow2<2><<<total / TPB, TPB, 0, stream>>>(y3, src, dst, agg);
        pool_k<<<(N_NODES + TPB - 1) / TPB, TPB, 0, stream>>>(agg, h2, cnt, W3r, b3, batch, pool, gcnt);
    }

    final_k<<<(N_GRAPHS + TPB - 1) / TPB, TPB, 0, stream>>>(pool, gcnt, Wc, bc, out);
}

// Round 3
// 1037.913 us; speedup vs baseline: 1.0437x; 1.0437x over previous
//
#include <hip/hip_runtime.h>

#define N_NODES 250000
#define N_EDGES 4000000
#define N_GRAPHS 512
#define NEG 0.01f
#define SCAN_T 1024
#define CHUNK 245  // ceil(N_NODES / SCAN_T)

__device__ __forceinline__ float lrelu(float v) { return v > 0.0f ? v : NEG * v; }

// ---- CSR build ----------------------------------------------------------

__global__ void hist_k(const int* __restrict__ dst, int* __restrict__ deg) {
    unsigned e = blockIdx.x * blockDim.x + threadIdx.x;
    if (e < N_EDGES) atomicAdd(&deg[dst[e]], 1);
}

__global__ void scan_part(const int* __restrict__ deg, int* __restrict__ tsum) {
    int t = blockIdx.x * blockDim.x + threadIdx.x;
    if (t >= SCAN_T) return;
    int a = t * CHUNK, b = min(a + CHUNK, N_NODES);
    int s = 0;
    for (int i = a; i < b; i++) s += deg[i];
    tsum[t] = s;
}

__global__ void scan_top(int* __restrict__ tsum) {
    __shared__ int sh[SCAN_T];
    int t = threadIdx.x;
    int v = tsum[t];
    sh[t] = v;
    __syncthreads();
    for (int off = 1; off < SCAN_T; off <<= 1) {
        int u = (t >= off) ? sh[t - off] : 0;
        __syncthreads();
        sh[t] += u;
        __syncthreads();
    }
    tsum[t] = sh[t] - v;  // exclusive
}

__global__ void scan_write(const int* __restrict__ deg, const int* __restrict__ tsum,
                           int* __restrict__ cursor) {
    int t = blockIdx.x * blockDim.x + threadIdx.x;
    if (t >= SCAN_T) return;
    int a = t * CHUNK, b = min(a + CHUNK, N_NODES);
    int run = tsum[t];
    for (int i = a; i < b; i++) { cursor[i] = run; run += deg[i]; }
}

// Advances cursor[n] to segment end; gathers use start = cursor[n] - deg[n].
__global__ void place_k(const int* __restrict__ src, const int* __restrict__ dst,
                        int* __restrict__ cursor, int* __restrict__ ssrc) {
    unsigned e = blockIdx.x * blockDim.x + threadIdx.x;
    if (e >= N_EDGES) return;
    int pos = atomicAdd(&cursor[dst[e]], 1);
    ssrc[pos] = src[e];
}

// ---- Gathers ------------------------------------------------------------

// 16 lanes per node, 13 active dims.
__global__ void gather13(const float* __restrict__ x, const int* __restrict__ ssrc,
                         const int* __restrict__ cursor, const int* __restrict__ deg,
                         float* __restrict__ agg) {
    unsigned tid = blockIdx.x * blockDim.x + threadIdx.x;
    unsigned n = tid >> 4;
    unsigned j = tid & 15u;
    if (n >= N_NODES || j >= 13u) return;
    int end = cursor[n];
    int start = end - deg[n];
    float acc = 0.0f;
    for (int k = start; k < end; k++) {
        int s = ssrc[k];
        acc += x[(unsigned)s * 13u + j];
    }
    agg[n * 13u + j] = acc;
}

// 2 lanes per node, float4 each (8 dims).
__global__ void gather8(const float* __restrict__ y2, const int* __restrict__ ssrc,
                        const int* __restrict__ cursor, const int* __restrict__ deg,
                        float* __restrict__ agg) {
    unsigned tid = blockIdx.x * blockDim.x + threadIdx.x;
    unsigned n = tid >> 1;
    unsigned l = tid & 1u;
    if (n >= N_NODES) return;
    int end = cursor[n];
    int start = end - deg[n];
    float4 acc = make_float4(0.f, 0.f, 0.f, 0.f);
    for (int k = start; k < end; k++) {
        int s = ssrc[k];
        float4 v = *(const float4*)&y2[(unsigned)s * 8u + l * 4u];
        acc.x += v.x; acc.y += v.y; acc.z += v.z; acc.w += v.w;
    }
    *(float4*)&agg[n * 8u + l * 4u] = acc;
}

// 1 thread per node, float4 (4 dims).
__global__ void gather4(const float* __restrict__ y3, const int* __restrict__ ssrc,
                        const int* __restrict__ cursor, const int* __restrict__ deg,
                        float* __restrict__ agg) {
    unsigned n = blockIdx.x * blockDim.x + threadIdx.x;
    if (n >= N_NODES) return;
    int end = cursor[n];
    int start = end - deg[n];
    float4 acc = make_float4(0.f, 0.f, 0.f, 0.f);
    for (int k = start; k < end; k++) {
        int s = ssrc[k];
        float4 v = *(const float4*)&y3[(unsigned)s * 4u];
        acc.x += v.x; acc.y += v.y; acc.z += v.z; acc.w += v.w;
    }
    *(float4*)&agg[n * 4u] = acc;
}

// ---- Node-side fused linears -------------------------------------------

// h1 = lrelu(agg13/cnt @W1l + b1 + x@W1r); y2 = h1@W2l; z2 = h1@W2r
__global__ void fused1(const float* __restrict__ agg, const float* __restrict__ x,
                       const int* __restrict__ deg,
                       const float* __restrict__ W1l, const float* __restrict__ b1,
                       const float* __restrict__ W1r, const float* __restrict__ W2l,
                       const float* __restrict__ W2r,
                       float* __restrict__ y2, float* __restrict__ z2) {
    __shared__ float sWl[208], sWr[208], sb[16], sA[128], sB[128];
    for (int i = threadIdx.x; i < 208; i += blockDim.x) { sWl[i] = W1l[i]; sWr[i] = W1r[i]; }
    for (int i = threadIdx.x; i < 128; i += blockDim.x) { sA[i] = W2l[i]; sB[i] = W2r[i]; }
    if (threadIdx.x < 16) sb[threadIdx.x] = b1[threadIdx.x];
    __syncthreads();
    int n = blockIdx.x * blockDim.x + threadIdx.x;
    if (n >= N_NODES) return;
    float inv = 1.0f / (float)max(deg[n], 1);
    float a[13], xv[13];
#pragma unroll
    for (int i = 0; i < 13; i++) { a[i] = agg[n * 13 + i] * inv; xv[i] = x[n * 13 + i]; }
    float h[16];
#pragma unroll
    for (int o = 0; o < 16; o++) {
        float acc = sb[o];
#pragma unroll
        for (int i = 0; i < 13; i++) acc += a[i] * sWl[i * 16 + o] + xv[i] * sWr[i * 16 + o];
        h[o] = lrelu(acc);
    }
#pragma unroll
    for (int o2 = 0; o2 < 8; o2++) {
        float ya = 0.0f, za = 0.0f;
#pragma unroll
        for (int o = 0; o < 16; o++) { ya += h[o] * sA[o * 8 + o2]; za += h[o] * sB[o * 8 + o2]; }
        y2[n * 8 + o2] = ya;
        z2[n * 8 + o2] = za;
    }
}

// h2 = lrelu(agg8/cnt + b2 + z2) (in-place over z2); y3 = h2@W3l
__global__ void fused2(const float* __restrict__ agg8, const int* __restrict__ deg,
                       const float* __restrict__ b2, const float* __restrict__ W3l,
                       float* __restrict__ z2h2, float* __restrict__ y3) {
    __shared__ float sb[8], sW3[32];
    if (threadIdx.x < 8) sb[threadIdx.x] = b2[threadIdx.x];
    if (threadIdx.x < 32) sW3[threadIdx.x] = W3l[threadIdx.x];
    __syncthreads();
    int n = blockIdx.x * blockDim.x + threadIdx.x;
    if (n >= N_NODES) return;
    float inv = 1.0f / (float)max(deg[n], 1);
    float h2v[8];
#pragma unroll
    for (int j = 0; j < 8; j++) {
        float v = agg8[n * 8 + j] * inv + sb[j] + z2h2[n * 8 + j];
        h2v[j] = lrelu(v);
        z2h2[n * 8 + j] = h2v[j];
    }
#pragma unroll
    for (int k = 0; k < 4; k++) {
        float acc = 0.0f;
#pragma unroll
        for (int j = 0; j < 8; j++) acc += h2v[j] * sW3[j * 4 + k];
        y3[n * 4 + k] = acc;
    }
}

// h3 = agg4/cnt + b3 + h2@W3r; pooled (sorted batch -> LDS window).
__global__ void pool_k(const float* __restrict__ agg4, const float* __restrict__ h2,
                       const int* __restrict__ deg,
                       const float* __restrict__ W3r, const float* __restrict__ b3,
                       const int* __restrict__ batch,
                       float* __restrict__ pool, float* __restrict__ gcnt) {
    __shared__ float sW[32], sb[4];
    __shared__ float lp[16][4];
    __shared__ float lc[16];
    __shared__ int sbase;
    if (threadIdx.x < 32) sW[threadIdx.x] = W3r[threadIdx.x];
    if (threadIdx.x < 4) sb[threadIdx.x] = b3[threadIdx.x];
    if (threadIdx.x < 16) {
        lc[threadIdx.x] = 0.0f;
        for (int k = 0; k < 4; k++) lp[threadIdx.x][k] = 0.0f;
    }
    int n0 = blockIdx.x * blockDim.x;
    if (threadIdx.x == 0) sbase = batch[n0 < N_NODES ? n0 : N_NODES - 1];
    __syncthreads();
    int n = n0 + threadIdx.x;
    if (n < N_NODES) {
        int b = batch[n];
        float inv = 1.0f / (float)max(deg[n], 1);
        float h2v[8];
#pragma unroll
        for (int j = 0; j < 8; j++) h2v[j] = h2[n * 8 + j];
        int off = b - sbase;
        bool local = (off >= 0 && off < 16);
#pragma unroll
        for (int k = 0; k < 4; k++) {
            float z = 0.0f;
#pragma unroll
            for (int j = 0; j < 8; j++) z += h2v[j] * sW[j * 4 + k];
            float v = agg4[n * 4 + k] * inv + sb[k] + z;
            if (local) atomicAdd(&lp[off][k], v);
            else atomicAdd(&pool[b * 4 + k], v);
        }
        if (local) atomicAdd(&lc[off], 1.0f);
        else atomicAdd(&gcnt[b], 1.0f);
    }
    __syncthreads();
    if (threadIdx.x < 16) {
        int b = sbase + threadIdx.x;
        float c = lc[threadIdx.x];
        if (c > 0.0f && b < N_GRAPHS) {
            atomicAdd(&gcnt[b], c);
            for (int k = 0; k < 4; k++) atomicAdd(&pool[b * 4 + k], lp[threadIdx.x][k]);
        }
    }
}

__global__ void final_k(const float* __restrict__ pool, const float* __restrict__ gcnt,
                        const float* __restrict__ Wc, const float* __restrict__ bc,
                        float* __restrict__ out) {
    int g = blockIdx.x * blockDim.x + threadIdx.x;
    if (g >= N_GRAPHS) return;
    float inv = 1.0f / fmaxf(gcnt[g], 1.0f);
    float acc = bc[0];
#pragma unroll
    for (int k = 0; k < 4; k++) {
        float ap = pool[g * 4 + k];
        acc += ap * inv * Wc[k] + ap * Wc[4 + k];
    }
    out[g] = acc;
}

extern "C" void kernel_launch(void* const* d_in, const int* in_sizes, int n_in,
                              void* d_out, int out_size, void* d_ws, size_t ws_size,
                              hipStream_t stream) {
    const float* x = (const float*)d_in[0];
    const int* ei = (const int*)d_in[1];
    const int* src = ei;
    const int* dst = ei + N_EDGES;
    const int* batch = (const int*)d_in[2];
    const float* W1l = (const float*)d_in[3];
    const float* b1 = (const float*)d_in[4];
    const float* W1r = (const float*)d_in[5];
    const float* W2l = (const float*)d_in[6];
    const float* b2 = (const float*)d_in[7];
    const float* W2r = (const float*)d_in[8];
    const float* W3l = (const float*)d_in[9];
    const float* b3 = (const float*)d_in[10];
    const float* W3r = (const float*)d_in[11];
    const float* Wc = (const float*)d_in[12];
    const float* bc = (const float*)d_in[13];
    float* out = (float*)d_out;

    const size_t N = N_NODES;
    // int region
    int* deg = (int*)d_ws;            // N
    int* cursor = deg + N;            // N
    int* tsum = cursor + N;           // 1024
    int* ssrc = tsum + 1024;          // E
    // float region (16B aligned: 2N+1024+E ints = 18,004,096 B)
    float* agg = (float*)(ssrc + N_EDGES);  // 13N (layers reuse; y3 overlays [8N,12N))
    float* y2 = agg + 13 * N;               // 8N
    float* z2 = y2 + 8 * N;                 // 8N (becomes h2 in place)
    float* y3 = agg + 8 * N;                // 4N (inside agg's upper region)
    float* pool = z2 + 8 * N;               // 2048
    float* gcnt = pool + N_GRAPHS * 4;      // 512

    const int TPB = 256;
    const int EB = (N_EDGES + TPB - 1) / TPB;
    const int NB = (N_NODES + TPB - 1) / TPB;

    hipMemsetAsync(deg, 0, N * sizeof(int), stream);
    hipMemsetAsync(pool, 0, N_GRAPHS * 5 * sizeof(float), stream);

    // CSR build
    hist_k<<<EB, TPB, 0, stream>>>(dst, deg);
    scan_part<<<SCAN_T / TPB, TPB, 0, stream>>>(deg, tsum);
    scan_top<<<1, SCAN_T, 0, stream>>>(tsum);
    scan_write<<<SCAN_T / TPB, TPB, 0, stream>>>(deg, tsum, cursor);
    place_k<<<EB, TPB, 0, stream>>>(src, dst, cursor, ssrc);

    // Layer 1: gather raw x (13 dims), fused node linear -> y2, z2
    gather13<<<(N_NODES * 16 + TPB - 1) / TPB, TPB, 0, stream>>>(x, ssrc, cursor, deg, agg);
    fused1<<<NB, TPB, 0, stream>>>(agg, x, deg, W1l, b1, W1r, W2l, W2r, y2, z2);

    // Layer 2: gather y2 (8 dims), epilogue -> h2 (in z2), y3
    gather8<<<(N_NODES * 2 + TPB - 1) / TPB, TPB, 0, stream>>>(y2, ssrc, cursor, deg, agg);
    fused2<<<NB, TPB, 0, stream>>>(agg, deg, b2, W3l, z2, y3);

    // Layer 3: gather y3 (4 dims), epilogue + pooling
    gather4<<<NB, TPB, 0, stream>>>(y3, ssrc, cursor, deg, agg);
    pool_k<<<NB, TPB, 0, stream>>>(agg, z2, deg, W3r, b3, batch, pool, gcnt);

    final_k<<<2, TPB, 0, stream>>>(pool, gcnt, Wc, bc, out);
}

// Round 4
// 813.602 us; speedup vs baseline: 1.3315x; 1.2757x over previous
//
#include <hip/hip_runtime.h>

#define N_NODES 250000
#define N_EDGES 4000000
#define N_GRAPHS 512
#define NEG 0.01f
#define BINB 10
#define NBINS 245            // ceil(250000 / 1024)
#define CAP 17408            // bin capacity: mean 16384 + 8 sigma (128)
#define PART_EPB 4096
#define PART_BLOCKS 977      // 977 * 4096 = 4,001,792 >= N_EDGES

__device__ __forceinline__ float lrelu(float v) { return v > 0.0f ? v : NEG * v; }

// ---- Edge binning: one pass, per-block chunk reservation ---------------
__global__ void partition_k(const int* __restrict__ src, const int* __restrict__ dst,
                            int* __restrict__ bin_cnt, unsigned* __restrict__ binned) {
    __shared__ int hist[NBINS];
    __shared__ int base[NBINS];
    __shared__ int cur[NBINS];
    int t = threadIdx.x;
    for (int i = t; i < NBINS; i += 256) { hist[i] = 0; cur[i] = 0; }
    __syncthreads();
    unsigned e0 = blockIdx.x * PART_EPB;
    int sw[16], dw[16];
#pragma unroll
    for (int i = 0; i < 16; i++) {
        unsigned e = e0 + (unsigned)i * 256u + t;
        if (e < N_EDGES) {
            sw[i] = src[e];
            dw[i] = dst[e];
            atomicAdd(&hist[dw[i] >> BINB], 1);
        } else {
            dw[i] = -1;
        }
    }
    __syncthreads();
    for (int i = t; i < NBINS; i += 256)
        if (hist[i] > 0) base[i] = atomicAdd(&bin_cnt[i], hist[i]);
    __syncthreads();
#pragma unroll
    for (int i = 0; i < 16; i++) {
        if (dw[i] >= 0) {
            int b = dw[i] >> BINB;
            int pos = atomicAdd(&cur[b], 1);
            binned[(unsigned)b * CAP + (unsigned)(base[b] + pos)] =
                ((unsigned)(dw[i] & 1023) << 18) | (unsigned)sw[i];
        }
    }
}

// ---- Layer-1 aggregation: 13 dims + degree, LDS accumulator ------------
__global__ __launch_bounds__(1024) void agg13_k(const float* __restrict__ x,
                                                const unsigned* __restrict__ binned,
                                                const int* __restrict__ bin_cnt,
                                                float* __restrict__ agg,
                                                float* __restrict__ cntf) {
    __shared__ float acc[1024 * 14];  // 56 KB
    int t = threadIdx.x;
    for (int i = t; i < 1024 * 14; i += 1024) acc[i] = 0.0f;
    __syncthreads();
    int bin = blockIdx.x;
    int cnt = bin_cnt[bin];
    const unsigned* bp = binned + (unsigned)bin * CAP;
    int j = t & 15;
    for (int k = t >> 4; k < cnt; k += 64) {
        unsigned w = bp[k];
        unsigned s = w & 0x3FFFFu;
        unsigned f = w >> 18;
        if (j < 13) atomicAdd(&acc[f * 14 + j], x[s * 13u + j]);
        else if (j == 13) atomicAdd(&acc[f * 14 + 13], 1.0f);
    }
    __syncthreads();
    int n0 = bin << BINB;
    int nodes = min(1024, N_NODES - n0);
    for (int idx = t; idx < nodes * 13; idx += 1024) {
        int r = idx / 13, c = idx - r * 13;
        agg[(unsigned)(n0 + r) * 13u + c] = acc[r * 14 + c];
    }
    for (int r = t; r < nodes; r += 1024) cntf[n0 + r] = acc[r * 14 + 13];
}

// ---- Layer-2/3 aggregation: D dims, LDS accumulator --------------------
template <int D, int LOGD>
__global__ __launch_bounds__(1024) void aggD_k(const float* __restrict__ feat,
                                               const unsigned* __restrict__ binned,
                                               const int* __restrict__ bin_cnt,
                                               float* __restrict__ agg) {
    __shared__ float acc[1024 * D];
    int t = threadIdx.x;
    for (int i = t; i < 1024 * D; i += 1024) acc[i] = 0.0f;
    __syncthreads();
    int bin = blockIdx.x;
    int cnt = bin_cnt[bin];
    const unsigned* bp = binned + (unsigned)bin * CAP;
    int j = t & (D - 1);
    for (int k = t >> LOGD; k < cnt; k += (1024 >> LOGD)) {
        unsigned w = bp[k];
        unsigned s = w & 0x3FFFFu;
        unsigned f = w >> 18;
        atomicAdd(&acc[f * D + j], feat[s * D + j]);
    }
    __syncthreads();
    int n0 = bin << BINB;
    int nodes = min(1024, N_NODES - n0);
    for (int idx = t; idx < nodes * D; idx += 1024)
        agg[(unsigned)n0 * D + idx] = acc[idx];
}

// ---- Node-side fused linears -------------------------------------------

// h1 = lrelu(agg13/cnt @W1l + b1 + x@W1r); y2 = h1@W2l; z2 = h1@W2r
__global__ void fused1(const float* __restrict__ agg, const float* __restrict__ x,
                       const float* __restrict__ cntf,
                       const float* __restrict__ W1l, const float* __restrict__ b1,
                       const float* __restrict__ W1r, const float* __restrict__ W2l,
                       const float* __restrict__ W2r,
                       float* __restrict__ y2, float* __restrict__ z2) {
    __shared__ float sWl[208], sWr[208], sb[16], sA[128], sB[128];
    for (int i = threadIdx.x; i < 208; i += blockDim.x) { sWl[i] = W1l[i]; sWr[i] = W1r[i]; }
    for (int i = threadIdx.x; i < 128; i += blockDim.x) { sA[i] = W2l[i]; sB[i] = W2r[i]; }
    if (threadIdx.x < 16) sb[threadIdx.x] = b1[threadIdx.x];
    __syncthreads();
    int n = blockIdx.x * blockDim.x + threadIdx.x;
    if (n >= N_NODES) return;
    float inv = 1.0f / fmaxf(cntf[n], 1.0f);
    float a[13], xv[13];
#pragma unroll
    for (int i = 0; i < 13; i++) { a[i] = agg[n * 13 + i] * inv; xv[i] = x[n * 13 + i]; }
    float h[16];
#pragma unroll
    for (int o = 0; o < 16; o++) {
        float acc = sb[o];
#pragma unroll
        for (int i = 0; i < 13; i++) acc += a[i] * sWl[i * 16 + o] + xv[i] * sWr[i * 16 + o];
        h[o] = lrelu(acc);
    }
#pragma unroll
    for (int o2 = 0; o2 < 8; o2++) {
        float ya = 0.0f, za = 0.0f;
#pragma unroll
        for (int o = 0; o < 16; o++) { ya += h[o] * sA[o * 8 + o2]; za += h[o] * sB[o * 8 + o2]; }
        y2[n * 8 + o2] = ya;
        z2[n * 8 + o2] = za;
    }
}

// h2 = lrelu(agg8/cnt + b2 + z2) (in place over z2); y3 = h2@W3l
__global__ void fused2(const float* __restrict__ agg8, const float* __restrict__ cntf,
                       const float* __restrict__ b2, const float* __restrict__ W3l,
                       float* __restrict__ z2h2, float* __restrict__ y3) {
    __shared__ float sb[8], sW3[32];
    if (threadIdx.x < 8) sb[threadIdx.x] = b2[threadIdx.x];
    if (threadIdx.x < 32) sW3[threadIdx.x] = W3l[threadIdx.x];
    __syncthreads();
    int n = blockIdx.x * blockDim.x + threadIdx.x;
    if (n >= N_NODES) return;
    float inv = 1.0f / fmaxf(cntf[n], 1.0f);
    float h2v[8];
#pragma unroll
    for (int j = 0; j < 8; j++) {
        float v = agg8[n * 8 + j] * inv + sb[j] + z2h2[n * 8 + j];
        h2v[j] = lrelu(v);
        z2h2[n * 8 + j] = h2v[j];
    }
#pragma unroll
    for (int k = 0; k < 4; k++) {
        float acc = 0.0f;
#pragma unroll
        for (int j = 0; j < 8; j++) acc += h2v[j] * sW3[j * 4 + k];
        y3[n * 4 + k] = acc;
    }
}

// h3 = agg4/cnt + b3 + h2@W3r; pooled (sorted batch -> LDS window).
__global__ void pool_k(const float* __restrict__ agg4, const float* __restrict__ h2,
                       const float* __restrict__ cntf,
                       const float* __restrict__ W3r, const float* __restrict__ b3,
                       const int* __restrict__ batch,
                       float* __restrict__ pool, float* __restrict__ gcnt) {
    __shared__ float sW[32], sb[4];
    __shared__ float lp[16][4];
    __shared__ float lc[16];
    __shared__ int sbase;
    if (threadIdx.x < 32) sW[threadIdx.x] = W3r[threadIdx.x];
    if (threadIdx.x < 4) sb[threadIdx.x] = b3[threadIdx.x];
    if (threadIdx.x < 16) {
        lc[threadIdx.x] = 0.0f;
        for (int k = 0; k < 4; k++) lp[threadIdx.x][k] = 0.0f;
    }
    int n0 = blockIdx.x * blockDim.x;
    if (threadIdx.x == 0) sbase = batch[n0 < N_NODES ? n0 : N_NODES - 1];
    __syncthreads();
    int n = n0 + threadIdx.x;
    if (n < N_NODES) {
        int b = batch[n];
        float inv = 1.0f / fmaxf(cntf[n], 1.0f);
        float h2v[8];
#pragma unroll
        for (int j = 0; j < 8; j++) h2v[j] = h2[n * 8 + j];
        int off = b - sbase;
        bool local = (off >= 0 && off < 16);
#pragma unroll
        for (int k = 0; k < 4; k++) {
            float z = 0.0f;
#pragma unroll
            for (int j = 0; j < 8; j++) z += h2v[j] * sW[j * 4 + k];
            float v = agg4[n * 4 + k] * inv + sb[k] + z;
            if (local) atomicAdd(&lp[off][k], v);
            else atomicAdd(&pool[b * 4 + k], v);
        }
        if (local) atomicAdd(&lc[off], 1.0f);
        else atomicAdd(&gcnt[b], 1.0f);
    }
    __syncthreads();
    if (threadIdx.x < 16) {
        int b = sbase + threadIdx.x;
        float c = lc[threadIdx.x];
        if (c > 0.0f && b < N_GRAPHS) {
            atomicAdd(&gcnt[b], c);
            for (int k = 0; k < 4; k++) atomicAdd(&pool[b * 4 + k], lp[threadIdx.x][k]);
        }
    }
}

__global__ void final_k(const float* __restrict__ pool, const float* __restrict__ gcnt,
                        const float* __restrict__ Wc, const float* __restrict__ bc,
                        float* __restrict__ out) {
    int g = blockIdx.x * blockDim.x + threadIdx.x;
    if (g >= N_GRAPHS) return;
    float inv = 1.0f / fmaxf(gcnt[g], 1.0f);
    float acc = bc[0];
#pragma unroll
    for (int k = 0; k < 4; k++) {
        float ap = pool[g * 4 + k];
        acc += ap * inv * Wc[k] + ap * Wc[4 + k];
    }
    out[g] = acc;
}

extern "C" void kernel_launch(void* const* d_in, const int* in_sizes, int n_in,
                              void* d_out, int out_size, void* d_ws, size_t ws_size,
                              hipStream_t stream) {
    const float* x = (const float*)d_in[0];
    const int* ei = (const int*)d_in[1];
    const int* src = ei;
    const int* dst = ei + N_EDGES;
    const int* batch = (const int*)d_in[2];
    const float* W1l = (const float*)d_in[3];
    const float* b1 = (const float*)d_in[4];
    const float* W1r = (const float*)d_in[5];
    const float* W2l = (const float*)d_in[6];
    const float* b2 = (const float*)d_in[7];
    const float* W2r = (const float*)d_in[8];
    const float* W3l = (const float*)d_in[9];
    const float* b3 = (const float*)d_in[10];
    const float* W3r = (const float*)d_in[11];
    const float* Wc = (const float*)d_in[12];
    const float* bc = (const float*)d_in[13];
    float* out = (float*)d_out;

    const size_t N = N_NODES;
    // layout: binned (NBINS*CAP u32 = 17.06 MB) | bin_cnt (256 int) | floats
    unsigned* binned = (unsigned*)d_ws;
    int* bin_cnt = (int*)(binned + (size_t)NBINS * CAP);
    float* fbase = (float*)(bin_cnt + 256);
    float* agg = fbase;                 // 13N (reused: agg8 in [0,8N), agg4 in [0,4N))
    float* y3 = agg + 8 * N;            // 4N overlay in agg's upper region
    float* cntf = fbase + 13 * N;       // N
    float* y2 = cntf + N;               // 8N
    float* z2 = y2 + 8 * N;             // 8N (becomes h2 in place)
    float* pool = z2 + 8 * N;           // 2048
    float* gcnt = pool + N_GRAPHS * 4;  // 512

    const int TPB = 256;
    const int NB = (N_NODES + TPB - 1) / TPB;

    hipMemsetAsync(bin_cnt, 0, 256 * sizeof(int), stream);
    hipMemsetAsync(pool, 0, N_GRAPHS * 5 * sizeof(float), stream);

    // Bin edges by dst>>10 (done once, reused by all 3 layers).
    partition_k<<<PART_BLOCKS, TPB, 0, stream>>>(src, dst, bin_cnt, binned);

    // Layer 1: LDS-aggregate raw x (13 dims) + degree, fused node linear.
    agg13_k<<<NBINS, 1024, 0, stream>>>(x, binned, bin_cnt, agg, cntf);
    fused1<<<NB, TPB, 0, stream>>>(agg, x, cntf, W1l, b1, W1r, W2l, W2r, y2, z2);

    // Layer 2: LDS-aggregate y2 (8 dims), epilogue -> h2 (in z2), y3.
    aggD_k<8, 3><<<NBINS, 1024, 0, stream>>>(y2, binned, bin_cnt, agg);
    fused2<<<NB, TPB, 0, stream>>>(agg, cntf, b2, W3l, z2, y3);

    // Layer 3: LDS-aggregate y3 (4 dims), epilogue + pooling.
    aggD_k<4, 2><<<NBINS, 1024, 0, stream>>>(y3, binned, bin_cnt, agg);
    pool_k<<<NB, TPB, 0, stream>>>(agg, z2, cntf, W3r, b3, batch, pool, gcnt);

    final_k<<<2, TPB, 0, stream>>>(pool, gcnt, Wc, bc, out);
}

// Round 5
// 800.916 us; speedup vs baseline: 1.3526x; 1.0158x over previous
//
#include <hip/hip_runtime.h>

#define N_NODES 250000
#define N_EDGES 4000000
#define N_GRAPHS 512
#define NEG 0.01f
#define BINB 9
#define WIN 512
#define NBINS 489            // ceil(250000 / 512)
#define CAP 9216             // bin capacity: mean 8192 + ~11 sigma (90)
#define PART_EPB 4096
#define PART_BLOCKS 977      // 977 * 4096 >= N_EDGES

__device__ __forceinline__ float lrelu(float v) { return v > 0.0f ? v : NEG * v; }

// ---- Pad x (13 floats/row) into x16 (16 floats/row, one cache line) ----
__global__ void pad_x(const float* __restrict__ x, float* __restrict__ x16) {
    int tid = blockIdx.x * blockDim.x + threadIdx.x;
    if (tid >= N_NODES * 16) return;
    int n = tid >> 4, j = tid & 15;
    x16[tid] = (j < 13) ? x[n * 13 + j] : 0.0f;
}

// ---- Edge binning: one pass, per-block chunk reservation ---------------
__global__ void partition_k(const int* __restrict__ src, const int* __restrict__ dst,
                            int* __restrict__ bin_cnt, unsigned* __restrict__ binned) {
    __shared__ int hist[NBINS];
    __shared__ int base[NBINS];
    __shared__ int cur[NBINS];
    int t = threadIdx.x;
    for (int i = t; i < NBINS; i += 256) { hist[i] = 0; cur[i] = 0; }
    __syncthreads();
    unsigned e0 = blockIdx.x * PART_EPB;
    int sw[16], dw[16];
#pragma unroll
    for (int i = 0; i < 16; i++) {
        unsigned e = e0 + (unsigned)i * 256u + t;
        if (e < N_EDGES) {
            sw[i] = src[e];
            dw[i] = dst[e];
            atomicAdd(&hist[dw[i] >> BINB], 1);
        } else {
            dw[i] = -1;
        }
    }
    __syncthreads();
    for (int i = t; i < NBINS; i += 256)
        if (hist[i] > 0) base[i] = atomicAdd(&bin_cnt[i], hist[i]);
    __syncthreads();
#pragma unroll
    for (int i = 0; i < 16; i++) {
        if (dw[i] >= 0) {
            int b = dw[i] >> BINB;
            int pos = atomicAdd(&cur[b], 1);
            binned[(unsigned)b * CAP + (unsigned)(base[b] + pos)] =
                ((unsigned)(dw[i] & (WIN - 1)) << 18) | (unsigned)sw[i];
        }
    }
}

// ---- Layer-1 aggregation: 4 lanes/edge float4 on x16, LDS accumulator --
__global__ __launch_bounds__(1024) void agg13_k(const float* __restrict__ x16,
                                                const unsigned* __restrict__ binned,
                                                const int* __restrict__ bin_cnt,
                                                float* __restrict__ agg,
                                                float* __restrict__ cntf) {
    __shared__ float acc[WIN * 14];  // 28 KB
    int t = threadIdx.x;
    for (int i = t; i < WIN * 14; i += 1024) acc[i] = 0.0f;
    __syncthreads();
    int bin = blockIdx.x;
    int cnt = bin_cnt[bin];
    const unsigned* bp = binned + (size_t)bin * CAP;
    int g = t >> 2, j4 = t & 3;
    unsigned w = (g < cnt) ? bp[g] : 0u;
    for (int k = g; k < cnt; k += 256) {
        unsigned wn = (k + 256 < cnt) ? bp[k + 256] : 0u;
        unsigned s = w & 0x3FFFFu;
        unsigned f = w >> 18;
        float4 v = *(const float4*)&x16[s * 16u + (unsigned)j4 * 4u];
        float* a = &acc[f * 14u + (unsigned)j4 * 4u];
        if (j4 < 3) {
            atomicAdd(a + 0, v.x); atomicAdd(a + 1, v.y);
            atomicAdd(a + 2, v.z); atomicAdd(a + 3, v.w);
        } else {
            atomicAdd(a + 0, v.x);   // dim 12
            atomicAdd(a + 1, 1.0f);  // degree count in col 13
        }
        w = wn;
    }
    __syncthreads();
    int n0 = bin << BINB;
    int nodes = min(WIN, N_NODES - n0);
    for (int idx = t; idx < nodes * 13; idx += 1024) {
        int r = idx / 13, c = idx - r * 13;
        agg[(size_t)n0 * 13u + idx] = acc[r * 14 + c];
    }
    for (int r = t; r < nodes; r += 1024) cntf[n0 + r] = acc[r * 14 + 13];
}

// ---- Layer-2/3 aggregation: D/4 lanes/edge float4, LDS accumulator -----
template <int D>
__global__ __launch_bounds__(1024) void aggD_k(const float* __restrict__ feat,
                                               const unsigned* __restrict__ binned,
                                               const int* __restrict__ bin_cnt,
                                               float* __restrict__ agg) {
    constexpr int LPE = D / 4;
    constexpr int SLOTS = 1024 / LPE;
    __shared__ float acc[WIN * D];
    int t = threadIdx.x;
    for (int i = t; i < WIN * D; i += 1024) acc[i] = 0.0f;
    __syncthreads();
    int bin = blockIdx.x;
    int cnt = bin_cnt[bin];
    const unsigned* bp = binned + (size_t)bin * CAP;
    int g = t / LPE, l = t % LPE;
    unsigned w = (g < cnt) ? bp[g] : 0u;
    for (int k = g; k < cnt; k += SLOTS) {
        unsigned wn = (k + SLOTS < cnt) ? bp[k + SLOTS] : 0u;
        unsigned s = w & 0x3FFFFu;
        unsigned f = w >> 18;
        float4 v = *(const float4*)&feat[s * D + l * 4];
        float* a = &acc[f * D + l * 4];
        atomicAdd(a + 0, v.x); atomicAdd(a + 1, v.y);
        atomicAdd(a + 2, v.z); atomicAdd(a + 3, v.w);
        w = wn;
    }
    __syncthreads();
    int n0 = bin << BINB;
    int nodes = min(WIN, N_NODES - n0);
    for (int idx = t; idx < nodes * D; idx += 1024)
        agg[(size_t)n0 * D + idx] = acc[idx];
}

// ---- Node-side fused linears -------------------------------------------

// h1 = lrelu(agg13/cnt @W1l + b1 + x@W1r); y2 = h1@W2l; z2 = h1@W2r
__global__ void fused1(const float* __restrict__ agg, const float* __restrict__ x,
                       const float* __restrict__ cntf,
                       const float* __restrict__ W1l, const float* __restrict__ b1,
                       const float* __restrict__ W1r, const float* __restrict__ W2l,
                       const float* __restrict__ W2r,
                       float* __restrict__ y2, float* __restrict__ z2) {
    __shared__ float sWl[208], sWr[208], sb[16], sA[128], sB[128];
    for (int i = threadIdx.x; i < 208; i += blockDim.x) { sWl[i] = W1l[i]; sWr[i] = W1r[i]; }
    for (int i = threadIdx.x; i < 128; i += blockDim.x) { sA[i] = W2l[i]; sB[i] = W2r[i]; }
    if (threadIdx.x < 16) sb[threadIdx.x] = b1[threadIdx.x];
    __syncthreads();
    int n = blockIdx.x * blockDim.x + threadIdx.x;
    if (n >= N_NODES) return;
    float inv = 1.0f / fmaxf(cntf[n], 1.0f);
    float a[13], xv[13];
#pragma unroll
    for (int i = 0; i < 13; i++) { a[i] = agg[n * 13 + i] * inv; xv[i] = x[n * 13 + i]; }
    float h[16];
#pragma unroll
    for (int o = 0; o < 16; o++) {
        float acc = sb[o];
#pragma unroll
        for (int i = 0; i < 13; i++) acc += a[i] * sWl[i * 16 + o] + xv[i] * sWr[i * 16 + o];
        h[o] = lrelu(acc);
    }
#pragma unroll
    for (int o2 = 0; o2 < 8; o2++) {
        float ya = 0.0f, za = 0.0f;
#pragma unroll
        for (int o = 0; o < 16; o++) { ya += h[o] * sA[o * 8 + o2]; za += h[o] * sB[o * 8 + o2]; }
        y2[n * 8 + o2] = ya;
        z2[n * 8 + o2] = za;
    }
}

// h2 = lrelu(agg8/cnt + b2 + z2) (in place over z2); y3 = h2@W3l
__global__ void fused2(const float* __restrict__ agg8, const float* __restrict__ cntf,
                       const float* __restrict__ b2, const float* __restrict__ W3l,
                       float* __restrict__ z2h2, float* __restrict__ y3) {
    __shared__ float sb[8], sW3[32];
    if (threadIdx.x < 8) sb[threadIdx.x] = b2[threadIdx.x];
    if (threadIdx.x < 32) sW3[threadIdx.x] = W3l[threadIdx.x];
    __syncthreads();
    int n = blockIdx.x * blockDim.x + threadIdx.x;
    if (n >= N_NODES) return;
    float inv = 1.0f / fmaxf(cntf[n], 1.0f);
    float h2v[8];
#pragma unroll
    for (int j = 0; j < 8; j++) {
        float v = agg8[n * 8 + j] * inv + sb[j] + z2h2[n * 8 + j];
        h2v[j] = lrelu(v);
        z2h2[n * 8 + j] = h2v[j];
    }
#pragma unroll
    for (int k = 0; k < 4; k++) {
        float acc = 0.0f;
#pragma unroll
        for (int j = 0; j < 8; j++) acc += h2v[j] * sW3[j * 4 + k];
        y3[n * 4 + k] = acc;
    }
}

// h3 = agg4/cnt + b3 + h2@W3r; pooled (sorted batch -> LDS window).
__global__ void pool_k(const float* __restrict__ agg4, const float* __restrict__ h2,
                       const float* __restrict__ cntf,
                       const float* __restrict__ W3r, const float* __restrict__ b3,
                       const int* __restrict__ batch,
                       float* __restrict__ pool, float* __restrict__ gcnt) {
    __shared__ float sW[32], sb[4];
    __shared__ float lp[16][4];
    __shared__ float lc[16];
    __shared__ int sbase;
    if (threadIdx.x < 32) sW[threadIdx.x] = W3r[threadIdx.x];
    if (threadIdx.x < 4) sb[threadIdx.x] = b3[threadIdx.x];
    if (threadIdx.x < 16) {
        lc[threadIdx.x] = 0.0f;
        for (int k = 0; k < 4; k++) lp[threadIdx.x][k] = 0.0f;
    }
    int n0 = blockIdx.x * blockDim.x;
    if (threadIdx.x == 0) sbase = batch[n0 < N_NODES ? n0 : N_NODES - 1];
    __syncthreads();
    int n = n0 + threadIdx.x;
    if (n < N_NODES) {
        int b = batch[n];
        float inv = 1.0f / fmaxf(cntf[n], 1.0f);
        float h2v[8];
#pragma unroll
        for (int j = 0; j < 8; j++) h2v[j] = h2[n * 8 + j];
        int off = b - sbase;
        bool local = (off >= 0 && off < 16);
#pragma unroll
        for (int k = 0; k < 4; k++) {
            float z = 0.0f;
#pragma unroll
            for (int j = 0; j < 8; j++) z += h2v[j] * sW[j * 4 + k];
            float v = agg4[n * 4 + k] * inv + sb[k] + z;
            if (local) atomicAdd(&lp[off][k], v);
            else atomicAdd(&pool[b * 4 + k], v);
        }
        if (local) atomicAdd(&lc[off], 1.0f);
        else atomicAdd(&gcnt[b], 1.0f);
    }
    __syncthreads();
    if (threadIdx.x < 16) {
        int b = sbase + threadIdx.x;
        float c = lc[threadIdx.x];
        if (c > 0.0f && b < N_GRAPHS) {
            atomicAdd(&gcnt[b], c);
            for (int k = 0; k < 4; k++) atomicAdd(&pool[b * 4 + k], lp[threadIdx.x][k]);
        }
    }
}

__global__ void final_k(const float* __restrict__ pool, const float* __restrict__ gcnt,
                        const float* __restrict__ Wc, const float* __restrict__ bc,
                        float* __restrict__ out) {
    int g = blockIdx.x * blockDim.x + threadIdx.x;
    if (g >= N_GRAPHS) return;
    float inv = 1.0f / fmaxf(gcnt[g], 1.0f);
    float acc = bc[0];
#pragma unroll
    for (int k = 0; k < 4; k++) {
        float ap = pool[g * 4 + k];
        acc += ap * inv * Wc[k] + ap * Wc[4 + k];
    }
    out[g] = acc;
}

extern "C" void kernel_launch(void* const* d_in, const int* in_sizes, int n_in,
                              void* d_out, int out_size, void* d_ws, size_t ws_size,
                              hipStream_t stream) {
    const float* x = (const float*)d_in[0];
    const int* ei = (const int*)d_in[1];
    const int* src = ei;
    const int* dst = ei + N_EDGES;
    const int* batch = (const int*)d_in[2];
    const float* W1l = (const float*)d_in[3];
    const float* b1 = (const float*)d_in[4];
    const float* W1r = (const float*)d_in[5];
    const float* W2l = (const float*)d_in[6];
    const float* b2 = (const float*)d_in[7];
    const float* W2r = (const float*)d_in[8];
    const float* W3l = (const float*)d_in[9];
    const float* b3 = (const float*)d_in[10];
    const float* W3r = (const float*)d_in[11];
    const float* Wc = (const float*)d_in[12];
    const float* bc = (const float*)d_in[13];
    float* out = (float*)d_out;

    const size_t N = N_NODES;
    // layout: binned (NBINS*CAP u32 ~= 18.0 MB) | bin_cnt (512) | floats
    unsigned* binned = (unsigned*)d_ws;
    int* bin_cnt = (int*)(binned + (size_t)NBINS * CAP);
    float* fbase = (float*)(bin_cnt + 512);
    float* agg = fbase;                 // 13N (reused: agg8 [0,8N), agg4 [0,4N))
    float* y3 = agg + 8 * N;            // 4N overlay in agg's upper region
    float* cntf = fbase + 13 * N;       // N
    float* y2 = cntf + N;               // 8N
    float* z2 = y2 + 8 * N;             // 8N (becomes h2 in place)
    float* x16 = y2;                    // 16N alias over y2+z2 (dead after agg13)
    float* pool = z2 + 8 * N;           // 2048
    float* gcnt = pool + N_GRAPHS * 4;  // 512

    const int TPB = 256;
    const int NB = (N_NODES + TPB - 1) / TPB;

    hipMemsetAsync(bin_cnt, 0, 512 * sizeof(int), stream);
    hipMemsetAsync(pool, 0, N_GRAPHS * 5 * sizeof(float), stream);

    // Prep: pad x to 64-B rows; bin edges by dst>>9 (reused by all layers).
    pad_x<<<(N_NODES * 16) / TPB, TPB, 0, stream>>>(x, x16);
    partition_k<<<PART_BLOCKS, TPB, 0, stream>>>(src, dst, bin_cnt, binned);

    // Layer 1: LDS-aggregate x16 (13 dims + degree), fused node linear.
    agg13_k<<<NBINS, 1024, 0, stream>>>(x16, binned, bin_cnt, agg, cntf);
    fused1<<<NB, TPB, 0, stream>>>(agg, x, cntf, W1l, b1, W1r, W2l, W2r, y2, z2);

    // Layer 2: LDS-aggregate y2 (8 dims), epilogue -> h2 (in z2), y3.
    aggD_k<8><<<NBINS, 1024, 0, stream>>>(y2, binned, bin_cnt, agg);
    fused2<<<NB, TPB, 0, stream>>>(agg, cntf, b2, W3l, z2, y3);

    // Layer 3: LDS-aggregate y3 (4 dims), epilogue + pooling.
    aggD_k<4><<<NBINS, 1024, 0, stream>>>(y3, binned, bin_cnt, agg);
    pool_k<<<NB, TPB, 0, stream>>>(agg, z2, cntf, W3r, b3, batch, pool, gcnt);

    final_k<<<2, TPB, 0, stream>>>(pool, gcnt, Wc, bc, out);
}